// Round 1
// baseline (4216.268 us; speedup 1.0000x reference)
//
#include <hip/hip_runtime.h>
#include <math.h>

#define NBUS 30000
#define NGEN 6000
#define NEL 250000
#define NEG 12000
#define HC 256

__device__ __forceinline__ void atomicMaxF(float* addr, float v) {
  if (v >= 0.f) atomicMax((int*)addr, __float_as_int(v));
  else atomicMin((unsigned int*)addr, __float_as_uint(v));
}

__global__ void fillk(float* __restrict__ p, float v, int n) {
  int i = blockIdx.x * blockDim.x + threadIdx.x;
  int st = gridDim.x * blockDim.x;
  for (; i < n; i += st) p[i] = v;
}

__global__ void gen_proj(const float* __restrict__ x, const float* __restrict__ w,
                         const float* __restrict__ b, float* __restrict__ o) {
  int idx = blockIdx.x * blockDim.x + threadIdx.x;
  if (idx >= NGEN * 32) return;
  int i = idx >> 5, c = idx & 31;
  float acc = b[c];
#pragma unroll
  for (int k = 0; k < 16; ++k) acc += x[i * 16 + k] * w[k * 32 + c];
  o[idx] = acc;
}

// C[M,256] = A[M,K] @ W[K,256], K multiple of 16, tile 64x64, thread 4x4.
__global__ __launch_bounds__(256) void sgemm_n256(
    const float* __restrict__ A, const float* __restrict__ W,
    float* __restrict__ Cm, int M, int K) {
  __shared__ float As[16][68];  // pad 68: 16B-aligned rows, conflict-free
  __shared__ float Ws[16][64];
  const int t = threadIdx.x;
  const int bm = blockIdx.x * 64, bn = blockIdx.y * 64;
  const int tx = t & 15, ty = t >> 4;
  const int lm = t >> 2, lk = (t & 3) << 2;
  const int wk = t >> 6, wn = t & 63;
  float acc[4][4] = {};
  for (int k0 = 0; k0 < K; k0 += 16) {
    float4 av = make_float4(0.f, 0.f, 0.f, 0.f);
    if (bm + lm < M) av = *(const float4*)(A + (size_t)(bm + lm) * K + k0 + lk);
    As[lk + 0][lm] = av.x; As[lk + 1][lm] = av.y;
    As[lk + 2][lm] = av.z; As[lk + 3][lm] = av.w;
#pragma unroll
    for (int i = 0; i < 4; ++i)
      Ws[wk + 4 * i][wn] = W[(size_t)(k0 + wk + 4 * i) * 256 + bn + wn];
    __syncthreads();
#pragma unroll
    for (int kk = 0; kk < 16; ++kk) {
      float4 a = *(const float4*)&As[kk][ty << 2];
      float4 b = *(const float4*)&Ws[kk][tx << 2];
      acc[0][0] += a.x * b.x; acc[0][1] += a.x * b.y; acc[0][2] += a.x * b.z; acc[0][3] += a.x * b.w;
      acc[1][0] += a.y * b.x; acc[1][1] += a.y * b.y; acc[1][2] += a.y * b.z; acc[1][3] += a.y * b.w;
      acc[2][0] += a.z * b.x; acc[2][1] += a.z * b.y; acc[2][2] += a.z * b.z; acc[2][3] += a.z * b.w;
      acc[3][0] += a.w * b.x; acc[3][1] += a.w * b.y; acc[3][2] += a.w * b.z; acc[3][3] += a.w * b.w;
    }
    __syncthreads();
  }
#pragma unroll
  for (int i = 0; i < 4; ++i) {
    int row = bm + (ty << 2) + i;
    if (row < M) {
      float4 o = make_float4(acc[i][0], acc[i][1], acc[i][2], acc[i][3]);
      *(float4*)(Cm + (size_t)row * 256 + bn + (tx << 2)) = o;
    }
  }
}

// One wave per edge: logits per head + atomic segment-max.
__global__ __launch_bounds__(256) void edge_logits(
    const int* __restrict__ src, const int* __restrict__ dst,
    const float* __restrict__ ea,
    const float* __restrict__ xl, const float* __restrict__ xr,
    const float* __restrict__ We, const float* __restrict__ att,
    const float* __restrict__ tptr,
    float* __restrict__ logits, float* __restrict__ mx, int E)
{
  int wid = (blockIdx.x * 256 + threadIdx.x) >> 6;
  int lane = threadIdx.x & 63;
  if (wid >= E) return;
  int s = src[wid], d = dst[wid];
  float temp = *tptr;
  const float* e = ea + (size_t)wid * 6;
  float e0 = e[0], e1 = e[1], e2 = e[2], e3 = e[3], e4 = e[4];
  float e5 = temp / fmaxf(e3, 1e-6f);  // physics prior overwrites col 5
  int c0 = lane << 2;
  float4 a = *(const float4*)(xl + (size_t)s * HC + c0);
  float4 b = *(const float4*)(xr + (size_t)d * HC + c0);
  float4 w0 = *(const float4*)(We + c0);
  float4 w1 = *(const float4*)(We + 256 + c0);
  float4 w2 = *(const float4*)(We + 512 + c0);
  float4 w3 = *(const float4*)(We + 768 + c0);
  float4 w4 = *(const float4*)(We + 1024 + c0);
  float4 w5 = *(const float4*)(We + 1280 + c0);
  float m0 = a.x + b.x + e0*w0.x + e1*w1.x + e2*w2.x + e3*w3.x + e4*w4.x + e5*w5.x;
  float m1 = a.y + b.y + e0*w0.y + e1*w1.y + e2*w2.y + e3*w3.y + e4*w4.y + e5*w5.y;
  float m2 = a.z + b.z + e0*w0.z + e1*w1.z + e2*w2.z + e3*w3.z + e4*w4.z + e5*w5.z;
  float m3 = a.w + b.w + e0*w0.w + e1*w1.w + e2*w2.w + e3*w3.w + e4*w4.w + e5*w5.w;
  m0 = m0 > 0.f ? m0 : 0.2f * m0;
  m1 = m1 > 0.f ? m1 : 0.2f * m1;
  m2 = m2 > 0.f ? m2 : 0.2f * m2;
  m3 = m3 > 0.f ? m3 : 0.2f * m3;
  float4 av = *(const float4*)(att + c0);  // att flat (4,64): index == c0
  float p = m0*av.x + m1*av.y + m2*av.z + m3*av.w;
  p += __shfl_xor(p, 1);
  p += __shfl_xor(p, 2);
  p += __shfl_xor(p, 4);
  p += __shfl_xor(p, 8);
  if ((lane & 15) == 0) {
    int h = lane >> 4;
    logits[(size_t)wid * 4 + h] = p;
    atomicMaxF(mx + (size_t)d * 4 + h, p);
  }
}

__global__ void edge_denom(const int* __restrict__ dst,
                           const float* __restrict__ logits,
                           const float* __restrict__ mx,
                           float* __restrict__ den, int E) {
  int idx = blockIdx.x * blockDim.x + threadIdx.x;
  if (idx >= E * 4) return;
  int ed = idx >> 2, h = idx & 3;
  int d = dst[ed];
  float ex = expf(logits[idx] - mx[d * 4 + h]);
  atomicAdd(den + d * 4 + h, ex);
}

// One wave per edge: alpha * xl[src] scatter-added to obuf[dst].
__global__ __launch_bounds__(256) void edge_aggr(
    const int* __restrict__ src, const int* __restrict__ dst,
    const float* __restrict__ logits, const float* __restrict__ mx,
    const float* __restrict__ den, const float* __restrict__ xl,
    float* __restrict__ obuf, int E)
{
  int wid = (blockIdx.x * 256 + threadIdx.x) >> 6;
  int lane = threadIdx.x & 63;
  if (wid >= E) return;
  int s = src[wid], d = dst[wid];
  int h = lane >> 4;
  float alpha = expf(logits[(size_t)wid * 4 + h] - mx[d * 4 + h]) /
                (den[d * 4 + h] + 1e-16f);
  int c0 = lane << 2;
  float4 x = *(const float4*)(xl + (size_t)s * HC + c0);
  float* o = obuf + (size_t)d * HC + c0;
  atomicAdd(o + 0, x.x * alpha);
  atomicAdd(o + 1, x.y * alpha);
  atomicAdd(o + 2, x.z * alpha);
  atomicAdd(o + 3, x.w * alpha);
}

// LN(256) + residual (direct or 32->256 proj) + optional ELU, in place.
__global__ __launch_bounds__(256) void ln_resid(
    float* __restrict__ io,
    const float* __restrict__ b1, const float* __restrict__ b2,
    const float* __restrict__ lnw, const float* __restrict__ lnb,
    const float* __restrict__ resx, int dres,
    const float* __restrict__ rp_w, const float* __restrict__ rp_b,
    int do_elu, int N)
{
  int i = blockIdx.x;
  if (i >= N) return;
  int c = threadIdx.x;
  __shared__ float red[4];
  __shared__ float rrow[32];
  float v = io[(size_t)i * 256 + c] + b1[c];
  if (b2) v += b2[c];
  float s = v;
#pragma unroll
  for (int m = 32; m >= 1; m >>= 1) s += __shfl_xor(s, m);
  if ((c & 63) == 0) red[c >> 6] = s;
  __syncthreads();
  float mu = (red[0] + red[1] + red[2] + red[3]) * (1.f / 256.f);
  __syncthreads();
  float dv = v - mu;
  float q = dv * dv;
#pragma unroll
  for (int m = 32; m >= 1; m >>= 1) q += __shfl_xor(q, m);
  if ((c & 63) == 0) red[c >> 6] = q;
  if (rp_w && c < dres) rrow[c] = resx[(size_t)i * dres + c];
  __syncthreads();
  float var = (red[0] + red[1] + red[2] + red[3]) * (1.f / 256.f);
  float y = dv * rsqrtf(var + 1e-5f) * lnw[c] + lnb[c];
  if (rp_w) {
    float r = rp_b[c];
    for (int k = 0; k < dres; ++k) r += rrow[k] * rp_w[k * 256 + c];
    y += r;
  } else {
    y += resx[(size_t)i * 256 + c];
  }
  if (do_elu) y = (y > 0.f) ? y : expm1f(y);
  io[(size_t)i * 256 + c] = y;
}

// Layer 2: head-mean + bias + LN(64) + rp2 residual (256->64), write d_out.
__global__ __launch_bounds__(64) void final_ln(
    const float* __restrict__ obuf,
    const float* __restrict__ b1, const float* __restrict__ b2,
    const float* __restrict__ lnw, const float* __restrict__ lnb,
    const float* __restrict__ resx,
    const float* __restrict__ rp_w, const float* __restrict__ rp_b,
    float* __restrict__ out, int N)
{
  int i = blockIdx.x;
  if (i >= N) return;
  int c = threadIdx.x;
  __shared__ float rrow[256];
  const float* orow = obuf + (size_t)i * 256;
  float v = 0.25f * (orow[c] + orow[64 + c] + orow[128 + c] + orow[192 + c]);
  v += b1[c];
  if (b2) v += b2[c];
  float s = v;
#pragma unroll
  for (int m = 32; m >= 1; m >>= 1) s += __shfl_xor(s, m);
  float mu = s * (1.f / 64.f);
  float dv = v - mu;
  float q = dv * dv;
#pragma unroll
  for (int m = 32; m >= 1; m >>= 1) q += __shfl_xor(q, m);
  float var = q * (1.f / 64.f);
  float y = dv * rsqrtf(var + 1e-5f) * lnw[c] + lnb[c];
  *(float4*)&rrow[c << 2] = *(const float4*)(resx + (size_t)i * 256 + (c << 2));
  __syncthreads();
  float r = rp_b[c];
#pragma unroll 8
  for (int k = 0; k < 256; ++k) r += rrow[k] * rp_w[k * 64 + c];
  out[(size_t)i * 64 + c] = y + r;
}

extern "C" void kernel_launch(void* const* d_in, const int* in_sizes, int n_in,
                              void* d_out, int out_size, void* d_ws, size_t ws_size,
                              hipStream_t stream) {
  const float* x_bus = (const float*)d_in[0];
  const float* x_gen = (const float*)d_in[1];
  const float* ea[3] = {(const float*)d_in[2], (const float*)d_in[3], (const float*)d_in[4]};
  const float* pw = (const float*)d_in[5];
  const float* pb = (const float*)d_in[6];
  const float* Wl[3] = {(const float*)d_in[7], (const float*)d_in[15], (const float*)d_in[23]};
  const float* Wr[3] = {(const float*)d_in[8], (const float*)d_in[16], (const float*)d_in[24]};
  const float* We[3] = {(const float*)d_in[9], (const float*)d_in[17], (const float*)d_in[25]};
  const float* att[3] = {(const float*)d_in[10], (const float*)d_in[18], (const float*)d_in[26]};
  const float* bc[3] = {(const float*)d_in[11], (const float*)d_in[19], (const float*)d_in[27]};
  const float* temp[3] = {(const float*)d_in[12], (const float*)d_in[20], (const float*)d_in[28]};
  const float* lnw[3] = {(const float*)d_in[13], (const float*)d_in[21], (const float*)d_in[29]};
  const float* lnb[3] = {(const float*)d_in[14], (const float*)d_in[22], (const float*)d_in[30]};
  const float* rp0_w = (const float*)d_in[31];
  const float* rp0_b = (const float*)d_in[32];
  const float* rp2_w = (const float*)d_in[33];
  const float* rp2_b = (const float*)d_in[34];
  const int* srcs[3] = {(const int*)d_in[35], (const int*)d_in[37], (const int*)d_in[39]};
  const int* dsts[3] = {(const int*)d_in[36], (const int*)d_in[38], (const int*)d_in[40]};

  float* ws = (float*)d_ws;
  size_t off = 0;
  auto alloc = [&](size_t n) { float* p = ws + off; off += n; return p; };
  float* xbA = alloc((size_t)NBUS * 256);
  float* xbB = alloc((size_t)NBUS * 256);
  float* xl_bus = alloc((size_t)NBUS * 256);
  float* xr_bus = alloc((size_t)NBUS * 256);
  float* xgA = alloc((size_t)NGEN * 256);
  float* xgB = alloc((size_t)NGEN * 256);
  float* xl_gen = alloc((size_t)NGEN * 256);
  float* xr_gen = alloc((size_t)NGEN * 256);
  float* xg0 = alloc((size_t)NGEN * 32);
  float* lg_line = alloc((size_t)NEL * 4);
  float* lg_eg = alloc((size_t)NEG * 4);
  float* mx_b = alloc((size_t)NBUS * 4);
  float* den_b = alloc((size_t)NBUS * 4);
  float* mx_g = alloc((size_t)NGEN * 4);
  float* den_g = alloc((size_t)NGEN * 4);
  (void)ws_size; (void)in_sizes; (void)n_in; (void)out_size;

  auto fill = [&](float* p, float v, int n) {
    int blocks = (n + 255) / 256; if (blocks > 4096) blocks = 4096;
    hipLaunchKernelGGL(fillk, dim3(blocks), dim3(256), 0, stream, p, v, n);
  };
  auto sgemm = [&](const float* A, const float* W, float* Cm, int M, int K) {
    dim3 g((M + 63) / 64, 4);
    hipLaunchKernelGGL(sgemm_n256, g, dim3(256), 0, stream, A, W, Cm, M, K);
  };
  auto run_conv = [&](int type, const float* xlbuf, const float* xrbuf,
                      const float* Wel, const float* attl, const float* templ,
                      float* lg, float* mx, float* den, float* obuf, int E) {
    int wb = (E + 3) / 4;
    hipLaunchKernelGGL(edge_logits, dim3(wb), dim3(256), 0, stream,
                       srcs[type], dsts[type], ea[type], xlbuf, xrbuf,
                       Wel, attl, templ, lg, mx, E);
    hipLaunchKernelGGL(edge_denom, dim3((E * 4 + 255) / 256), dim3(256), 0, stream,
                       dsts[type], lg, mx, den, E);
    hipLaunchKernelGGL(edge_aggr, dim3(wb), dim3(256), 0, stream,
                       srcs[type], dsts[type], lg, mx, den, xlbuf, obuf, E);
  };

  hipLaunchKernelGGL(gen_proj, dim3((NGEN * 32 + 255) / 256), dim3(256), 0, stream,
                     x_gen, pw, pb, xg0);

  const int din_l[3] = {32, 256, 256};
  const float* cur_xb = x_bus;
  const float* cur_xg = xg0;
  for (int l = 0; l < 3; ++l) {
    const int din = din_l[l];
    float* obuf_b = (l == 1) ? xbB : xbA;
    float* obuf_g = (l == 1) ? xgB : xgA;
    // --- type 0: line (bus->bus) ---
    sgemm(cur_xb, Wl[l], xl_bus, NBUS, din);
    sgemm(cur_xb, Wr[l], xr_bus, NBUS, din);
    fill(obuf_b, 0.f, NBUS * 256);
    fill(mx_b, -INFINITY, NBUS * 4);
    fill(den_b, 0.f, NBUS * 4);
    run_conv(0, xl_bus, xr_bus, We[l], att[l], temp[l],
             lg_line, mx_b, den_b, obuf_b, NEL);
    // --- type 1: g2b (gen->bus) ---
    sgemm(cur_xg, Wl[l] + (size_t)din * 256, xl_gen, NGEN, din);
    sgemm(cur_xb, Wr[l] + (size_t)din * 256, xr_bus, NBUS, din);
    fill(mx_b, -INFINITY, NBUS * 4);
    fill(den_b, 0.f, NBUS * 4);
    run_conv(1, xl_gen, xr_bus, We[l] + 1536, att[l] + 256, temp[l] + 1,
             lg_eg, mx_b, den_b, obuf_b, NEG);
    // --- type 2: b2g (bus->gen) ---
    sgemm(cur_xb, Wl[l] + (size_t)2 * din * 256, xl_bus, NBUS, din);
    sgemm(cur_xg, Wr[l] + (size_t)2 * din * 256, xr_gen, NGEN, din);
    fill(obuf_g, 0.f, NGEN * 256);
    fill(mx_g, -INFINITY, NGEN * 4);
    fill(den_g, 0.f, NGEN * 4);
    run_conv(2, xl_bus, xr_gen, We[l] + 3072, att[l] + 512, temp[l] + 2,
             lg_eg, mx_g, den_g, obuf_g, NEG);
    // --- node update ---
    if (l < 2) {
      const float* rpw_b = (l == 0) ? rp0_w : nullptr;
      const float* rpb_b = (l == 0) ? rp0_b : nullptr;
      const float* rpw_g = (l == 0) ? rp0_w + 32 * 256 : nullptr;
      const float* rpb_g = (l == 0) ? rp0_b + 256 : nullptr;
      hipLaunchKernelGGL(ln_resid, dim3(NBUS), dim3(256), 0, stream,
                         obuf_b, bc[l], bc[l] + 256, lnw[l], lnb[l],
                         cur_xb, 32, rpw_b, rpb_b, 1, NBUS);
      hipLaunchKernelGGL(ln_resid, dim3(NGEN), dim3(256), 0, stream,
                         obuf_g, bc[l] + 512, nullptr, lnw[l] + 256, lnb[l] + 256,
                         cur_xg, 32, rpw_g, rpb_g, 1, NGEN);
      cur_xb = obuf_b;
      cur_xg = obuf_g;
    } else {
      float* out = (float*)d_out;
      hipLaunchKernelGGL(final_ln, dim3(NBUS), dim3(64), 0, stream,
                         obuf_b, bc[2], bc[2] + 64, lnw[2], lnb[2],
                         cur_xb, rp2_w, rp2_b, out, NBUS);
      hipLaunchKernelGGL(final_ln, dim3(NGEN), dim3(64), 0, stream,
                         obuf_g, bc[2] + 128, nullptr, lnw[2] + 64, lnb[2] + 64,
                         cur_xg, rp2_w + 256 * 64, rp2_b + 64,
                         out + (size_t)NBUS * 64, NGEN);
    }
  }
}

// Round 2
// 1709.489 us; speedup vs baseline: 2.4664x; 2.4664x over previous
//
#include <hip/hip_runtime.h>
#include <math.h>

#define NBUS 30000
#define NGEN 6000
#define NEL 250000
#define NEG 12000
#define HC 256

__global__ void zeroi(int* __restrict__ p, int n) {
  int i = blockIdx.x * blockDim.x + threadIdx.x;
  int st = gridDim.x * blockDim.x;
  for (; i < n; i += st) p[i] = 0;
}

__global__ void hist_k(const int* __restrict__ dst, int* __restrict__ cnt, int E) {
  int i = blockIdx.x * blockDim.x + threadIdx.x;
  if (i < E) atomicAdd(&cnt[dst[i]], 1);
}

// Single-block scan: rowptr[0]=0, rowptr[i+1]=incl_sum(cnt[0..i]), cursor[i]=excl.
// cnt and cursor may alias (each element read once before written by same thread).
__global__ __launch_bounds__(1024) void scan_k(
    const int* __restrict__ cnt, int* __restrict__ rowptr,
    int* __restrict__ cursor, int n) {
  __shared__ int wtot[16];
  __shared__ int s_carry;
  int tid = threadIdx.x, lane = tid & 63, wv = tid >> 6;
  if (tid == 0) { s_carry = 0; rowptr[0] = 0; }
  __syncthreads();
  for (int base = 0; base < n; base += 1024) {
    int i = base + tid;
    int v = (i < n) ? cnt[i] : 0;
    int x = v;
#pragma unroll
    for (int off = 1; off < 64; off <<= 1) {
      int y = __shfl_up(x, off, 64);
      if (lane >= off) x += y;
    }
    if (lane == 63) wtot[wv] = x;
    __syncthreads();
    if (tid < 16) {
      int t = wtot[tid];
#pragma unroll
      for (int off = 1; off < 16; off <<= 1) {
        int y = __shfl_up(t, off, 64);
        if (tid >= off) t += y;
      }
      wtot[tid] = t;
    }
    __syncthreads();
    int woff = (wv == 0) ? 0 : wtot[wv - 1];
    int incl = s_carry + woff + x;
    if (i < n) { rowptr[i + 1] = incl; cursor[i] = incl - v; }
    __syncthreads();
    if (tid == 0) s_carry += wtot[15];
    __syncthreads();
  }
}

__global__ void scatter_k(const int* __restrict__ dst, int* __restrict__ cursor,
                          int* __restrict__ eidx, int E) {
  int i = blockIdx.x * blockDim.x + threadIdx.x;
  if (i < E) {
    int p = atomicAdd(&cursor[dst[i]], 1);
    eidx[p] = i;
  }
}

__global__ void gen_proj(const float* __restrict__ x, const float* __restrict__ w,
                         const float* __restrict__ b, float* __restrict__ o) {
  int idx = blockIdx.x * blockDim.x + threadIdx.x;
  if (idx >= NGEN * 32) return;
  int i = idx >> 5, c = idx & 31;
  float acc = b[c];
#pragma unroll
  for (int k = 0; k < 16; ++k) acc += x[i * 16 + k] * w[k * 32 + c];
  o[idx] = acc;
}

// C[M,256] = A[M,K] @ W[K,256], K multiple of 16, tile 64x64, thread 4x4.
__global__ __launch_bounds__(256) void sgemm_n256(
    const float* __restrict__ A, const float* __restrict__ W,
    float* __restrict__ Cm, int M, int K) {
  __shared__ float As[16][68];
  __shared__ float Ws[16][64];
  const int t = threadIdx.x;
  const int bm = blockIdx.x * 64, bn = blockIdx.y * 64;
  const int tx = t & 15, ty = t >> 4;
  const int lm = t >> 2, lk = (t & 3) << 2;
  const int wk = t >> 6, wn = t & 63;
  float acc[4][4] = {};
  for (int k0 = 0; k0 < K; k0 += 16) {
    float4 av = make_float4(0.f, 0.f, 0.f, 0.f);
    if (bm + lm < M) av = *(const float4*)(A + (size_t)(bm + lm) * K + k0 + lk);
    As[lk + 0][lm] = av.x; As[lk + 1][lm] = av.y;
    As[lk + 2][lm] = av.z; As[lk + 3][lm] = av.w;
#pragma unroll
    for (int i = 0; i < 4; ++i)
      Ws[wk + 4 * i][wn] = W[(size_t)(k0 + wk + 4 * i) * 256 + bn + wn];
    __syncthreads();
#pragma unroll
    for (int kk = 0; kk < 16; ++kk) {
      float4 a = *(const float4*)&As[kk][ty << 2];
      float4 b = *(const float4*)&Ws[kk][tx << 2];
      acc[0][0] += a.x * b.x; acc[0][1] += a.x * b.y; acc[0][2] += a.x * b.z; acc[0][3] += a.x * b.w;
      acc[1][0] += a.y * b.x; acc[1][1] += a.y * b.y; acc[1][2] += a.y * b.z; acc[1][3] += a.y * b.w;
      acc[2][0] += a.z * b.x; acc[2][1] += a.z * b.y; acc[2][2] += a.z * b.z; acc[2][3] += a.z * b.w;
      acc[3][0] += a.w * b.x; acc[3][1] += a.w * b.y; acc[3][2] += a.w * b.z; acc[3][3] += a.w * b.w;
    }
    __syncthreads();
  }
#pragma unroll
  for (int i = 0; i < 4; ++i) {
    int row = bm + (ty << 2) + i;
    if (row < M) {
      float4 o = make_float4(acc[i][0], acc[i][1], acc[i][2], acc[i][3]);
      *(float4*)(Cm + (size_t)row * 256 + bn + (tx << 2)) = o;
    }
  }
}

// One wave per edge: per-head attention logits -> lg[E][4]. No atomics.
__global__ __launch_bounds__(256) void edge_logits(
    const int* __restrict__ src, const int* __restrict__ dst,
    const float* __restrict__ ea,
    const float* __restrict__ xl, const float* __restrict__ xr,
    const float* __restrict__ We, const float* __restrict__ att,
    const float* __restrict__ tptr,
    float* __restrict__ logits, int E)
{
  int wid = (blockIdx.x * 256 + threadIdx.x) >> 6;
  int lane = threadIdx.x & 63;
  if (wid >= E) return;
  int s = src[wid], d = dst[wid];
  float temp = *tptr;
  const float* e = ea + (size_t)wid * 6;
  float e0 = e[0], e1 = e[1], e2 = e[2], e3 = e[3], e4 = e[4];
  float e5 = temp / fmaxf(e3, 1e-6f);  // physics prior overwrites col 5
  int c0 = lane << 2;
  float4 a = *(const float4*)(xl + (size_t)s * HC + c0);
  float4 b = *(const float4*)(xr + (size_t)d * HC + c0);
  float4 w0 = *(const float4*)(We + c0);
  float4 w1 = *(const float4*)(We + 256 + c0);
  float4 w2 = *(const float4*)(We + 512 + c0);
  float4 w3 = *(const float4*)(We + 768 + c0);
  float4 w4 = *(const float4*)(We + 1024 + c0);
  float4 w5 = *(const float4*)(We + 1280 + c0);
  float m0 = a.x + b.x + e0*w0.x + e1*w1.x + e2*w2.x + e3*w3.x + e4*w4.x + e5*w5.x;
  float m1 = a.y + b.y + e0*w0.y + e1*w1.y + e2*w2.y + e3*w3.y + e4*w4.y + e5*w5.y;
  float m2 = a.z + b.z + e0*w0.z + e1*w1.z + e2*w2.z + e3*w3.z + e4*w4.z + e5*w5.z;
  float m3 = a.w + b.w + e0*w0.w + e1*w1.w + e2*w2.w + e3*w3.w + e4*w4.w + e5*w5.w;
  m0 = m0 > 0.f ? m0 : 0.2f * m0;
  m1 = m1 > 0.f ? m1 : 0.2f * m1;
  m2 = m2 > 0.f ? m2 : 0.2f * m2;
  m3 = m3 > 0.f ? m3 : 0.2f * m3;
  float4 av = *(const float4*)(att + c0);
  float p = m0*av.x + m1*av.y + m2*av.z + m3*av.w;
  p += __shfl_xor(p, 1);
  p += __shfl_xor(p, 2);
  p += __shfl_xor(p, 4);
  p += __shfl_xor(p, 8);
  if ((lane & 15) == 0) logits[(size_t)wid * 4 + (lane >> 4)] = p;
}

// One wave per destination node: softmax over its incoming edges + weighted
// gather-accumulate. Writes (or read-modify-writes) obuf[node] once. No atomics.
__global__ __launch_bounds__(256) void node_aggr(
    const int* __restrict__ rowptr, const int* __restrict__ eidx,
    const int* __restrict__ src, const float* __restrict__ lg,
    const float* __restrict__ xl, float* __restrict__ obuf,
    int accumulate, int N)
{
  int node = (blockIdx.x * 256 + threadIdx.x) >> 6;
  int lane = threadIdx.x & 63;
  if (node >= N) return;
  int beg = rowptr[node], end = rowptr[node + 1];
  int h = lane >> 4;
  int c0 = lane << 2;
  float mx = -INFINITY;
  for (int i = beg; i < end; ++i) {
    int e = eidx[i];
    mx = fmaxf(mx, lg[(size_t)e * 4 + h]);
  }
  if (!isfinite(mx)) mx = 0.f;  // ref: where(isfinite(mx), mx, 0)
  float den = 0.f;
  float4 acc = make_float4(0.f, 0.f, 0.f, 0.f);
  for (int i = beg; i < end; ++i) {
    int e = eidx[i];
    float w = expf(lg[(size_t)e * 4 + h] - mx);
    den += w;
    int s = src[e];
    float4 x = *(const float4*)(xl + (size_t)s * HC + c0);
    acc.x += w * x.x; acc.y += w * x.y; acc.z += w * x.z; acc.w += w * x.w;
  }
  float inv = 1.f / (den + 1e-16f);
  acc.x *= inv; acc.y *= inv; acc.z *= inv; acc.w *= inv;
  float* o = obuf + (size_t)node * HC + c0;
  if (accumulate) {
    float4 p = *(const float4*)o;
    acc.x += p.x; acc.y += p.y; acc.z += p.z; acc.w += p.w;
  }
  *(float4*)o = acc;
}

// LN(256) + residual (direct or 32->256 proj) + optional ELU, in place.
__global__ __launch_bounds__(256) void ln_resid(
    float* __restrict__ io,
    const float* __restrict__ b1, const float* __restrict__ b2,
    const float* __restrict__ lnw, const float* __restrict__ lnb,
    const float* __restrict__ resx, int dres,
    const float* __restrict__ rp_w, const float* __restrict__ rp_b,
    int do_elu, int N)
{
  int i = blockIdx.x;
  if (i >= N) return;
  int c = threadIdx.x;
  __shared__ float red[4];
  __shared__ float rrow[32];
  float v = io[(size_t)i * 256 + c] + b1[c];
  if (b2) v += b2[c];
  float s = v;
#pragma unroll
  for (int m = 32; m >= 1; m >>= 1) s += __shfl_xor(s, m);
  if ((c & 63) == 0) red[c >> 6] = s;
  __syncthreads();
  float mu = (red[0] + red[1] + red[2] + red[3]) * (1.f / 256.f);
  __syncthreads();
  float dv = v - mu;
  float q = dv * dv;
#pragma unroll
  for (int m = 32; m >= 1; m >>= 1) q += __shfl_xor(q, m);
  if ((c & 63) == 0) red[c >> 6] = q;
  if (rp_w && c < dres) rrow[c] = resx[(size_t)i * dres + c];
  __syncthreads();
  float var = (red[0] + red[1] + red[2] + red[3]) * (1.f / 256.f);
  float y = dv * rsqrtf(var + 1e-5f) * lnw[c] + lnb[c];
  if (rp_w) {
    float r = rp_b[c];
    for (int k = 0; k < dres; ++k) r += rrow[k] * rp_w[k * 256 + c];
    y += r;
  } else {
    y += resx[(size_t)i * 256 + c];
  }
  if (do_elu) y = (y > 0.f) ? y : expm1f(y);
  io[(size_t)i * 256 + c] = y;
}

// Layer 2: head-mean + bias + LN(64) + rp2 residual (256->64), write d_out.
__global__ __launch_bounds__(64) void final_ln(
    const float* __restrict__ obuf,
    const float* __restrict__ b1, const float* __restrict__ b2,
    const float* __restrict__ lnw, const float* __restrict__ lnb,
    const float* __restrict__ resx,
    const float* __restrict__ rp_w, const float* __restrict__ rp_b,
    float* __restrict__ out, int N)
{
  int i = blockIdx.x;
  if (i >= N) return;
  int c = threadIdx.x;
  __shared__ float rrow[256];
  const float* orow = obuf + (size_t)i * 256;
  float v = 0.25f * (orow[c] + orow[64 + c] + orow[128 + c] + orow[192 + c]);
  v += b1[c];
  if (b2) v += b2[c];
  float s = v;
#pragma unroll
  for (int m = 32; m >= 1; m >>= 1) s += __shfl_xor(s, m);
  float mu = s * (1.f / 64.f);
  float dv = v - mu;
  float q = dv * dv;
#pragma unroll
  for (int m = 32; m >= 1; m >>= 1) q += __shfl_xor(q, m);
  float var = q * (1.f / 64.f);
  float y = dv * rsqrtf(var + 1e-5f) * lnw[c] + lnb[c];
  *(float4*)&rrow[c << 2] = *(const float4*)(resx + (size_t)i * 256 + (c << 2));
  __syncthreads();
  float r = rp_b[c];
#pragma unroll 8
  for (int k = 0; k < 256; ++k) r += rrow[k] * rp_w[k * 64 + c];
  out[(size_t)i * 64 + c] = y + r;
}

extern "C" void kernel_launch(void* const* d_in, const int* in_sizes, int n_in,
                              void* d_out, int out_size, void* d_ws, size_t ws_size,
                              hipStream_t stream) {
  const float* x_bus = (const float*)d_in[0];
  const float* x_gen = (const float*)d_in[1];
  const float* ea[3] = {(const float*)d_in[2], (const float*)d_in[3], (const float*)d_in[4]};
  const float* pw = (const float*)d_in[5];
  const float* pb = (const float*)d_in[6];
  const float* Wl[3] = {(const float*)d_in[7], (const float*)d_in[15], (const float*)d_in[23]};
  const float* Wr[3] = {(const float*)d_in[8], (const float*)d_in[16], (const float*)d_in[24]};
  const float* We[3] = {(const float*)d_in[9], (const float*)d_in[17], (const float*)d_in[25]};
  const float* att[3] = {(const float*)d_in[10], (const float*)d_in[18], (const float*)d_in[26]};
  const float* bc[3] = {(const float*)d_in[11], (const float*)d_in[19], (const float*)d_in[27]};
  const float* temp[3] = {(const float*)d_in[12], (const float*)d_in[20], (const float*)d_in[28]};
  const float* lnw[3] = {(const float*)d_in[13], (const float*)d_in[21], (const float*)d_in[29]};
  const float* lnb[3] = {(const float*)d_in[14], (const float*)d_in[22], (const float*)d_in[30]};
  const float* rp0_w = (const float*)d_in[31];
  const float* rp0_b = (const float*)d_in[32];
  const float* rp2_w = (const float*)d_in[33];
  const float* rp2_b = (const float*)d_in[34];
  const int* srcs[3] = {(const int*)d_in[35], (const int*)d_in[37], (const int*)d_in[39]};
  const int* dsts[3] = {(const int*)d_in[36], (const int*)d_in[38], (const int*)d_in[40]};

  float* ws = (float*)d_ws;
  size_t off = 0;
  auto alloc = [&](size_t n) { float* p = ws + off; off += n; return p; };
  float* xbA = alloc((size_t)NBUS * 256);
  float* xbB = alloc((size_t)NBUS * 256);
  float* xl_bus = alloc((size_t)NBUS * 256);
  float* xr_bus = alloc((size_t)NBUS * 256);
  float* xgA = alloc((size_t)NGEN * 256);
  float* xgB = alloc((size_t)NGEN * 256);
  float* xl_gen = alloc((size_t)NGEN * 256);
  float* xr_gen = alloc((size_t)NGEN * 256);
  float* xg0 = alloc((size_t)NGEN * 32);
  float* lg_line = alloc((size_t)NEL * 4);
  float* lg_eg = alloc((size_t)NEG * 4);
  // CSR int arrays (counts double as scatter cursors)
  int* cw_line = (int*)alloc(NBUS);
  int* rp_line = (int*)alloc(NBUS + 1);
  int* ei_line = (int*)alloc(NEL);
  int* cw_g2b = (int*)alloc(NBUS);
  int* rp_g2b = (int*)alloc(NBUS + 1);
  int* ei_g2b = (int*)alloc(NEG);
  int* cw_b2g = (int*)alloc(NGEN);
  int* rp_b2g = (int*)alloc(NGEN + 1);
  int* ei_b2g = (int*)alloc(NEG);
  (void)ws_size; (void)in_sizes; (void)n_in; (void)out_size;

  auto build_csr = [&](const int* dst, int* cw, int* rp, int* ei, int E, int N) {
    hipLaunchKernelGGL(zeroi, dim3((N + 1023) / 1024 > 256 ? 256 : (N + 1023) / 1024),
                       dim3(1024), 0, stream, cw, N);
    hipLaunchKernelGGL(hist_k, dim3((E + 255) / 256), dim3(256), 0, stream, dst, cw, E);
    hipLaunchKernelGGL(scan_k, dim3(1), dim3(1024), 0, stream, cw, rp, cw, N);
    hipLaunchKernelGGL(scatter_k, dim3((E + 255) / 256), dim3(256), 0, stream, dst, cw, ei, E);
  };
  build_csr(dsts[0], cw_line, rp_line, ei_line, NEL, NBUS);
  build_csr(dsts[1], cw_g2b, rp_g2b, ei_g2b, NEG, NBUS);
  build_csr(dsts[2], cw_b2g, rp_b2g, ei_b2g, NEG, NGEN);

  auto sgemm = [&](const float* A, const float* W, float* Cm, int M, int K) {
    dim3 g((M + 63) / 64, 4);
    hipLaunchKernelGGL(sgemm_n256, g, dim3(256), 0, stream, A, W, Cm, M, K);
  };
  auto run_conv = [&](int type, const float* xlbuf, const float* xrbuf,
                      const float* Wel, const float* attl, const float* templ,
                      float* lg, const int* rp, const int* ei,
                      float* obuf, int accumulate, int E, int N) {
    hipLaunchKernelGGL(edge_logits, dim3((E + 3) / 4), dim3(256), 0, stream,
                       srcs[type], dsts[type], ea[type], xlbuf, xrbuf,
                       Wel, attl, templ, lg, E);
    hipLaunchKernelGGL(node_aggr, dim3((N + 3) / 4), dim3(256), 0, stream,
                       rp, ei, srcs[type], lg, xlbuf, obuf, accumulate, N);
  };

  hipLaunchKernelGGL(gen_proj, dim3((NGEN * 32 + 255) / 256), dim3(256), 0, stream,
                     x_gen, pw, pb, xg0);

  const int din_l[3] = {32, 256, 256};
  const float* cur_xb = x_bus;
  const float* cur_xg = xg0;
  for (int l = 0; l < 3; ++l) {
    const int din = din_l[l];
    float* obuf_b = (l == 1) ? xbB : xbA;
    float* obuf_g = (l == 1) ? xgB : xgA;
    // --- type 0: line (bus->bus) ---
    sgemm(cur_xb, Wl[l], xl_bus, NBUS, din);
    sgemm(cur_xb, Wr[l], xr_bus, NBUS, din);
    run_conv(0, xl_bus, xr_bus, We[l], att[l], temp[l],
             lg_line, rp_line, ei_line, obuf_b, 0, NEL, NBUS);
    // --- type 1: g2b (gen->bus), accumulate into obuf_b ---
    sgemm(cur_xg, Wl[l] + (size_t)din * 256, xl_gen, NGEN, din);
    sgemm(cur_xb, Wr[l] + (size_t)din * 256, xr_bus, NBUS, din);
    run_conv(1, xl_gen, xr_bus, We[l] + 1536, att[l] + 256, temp[l] + 1,
             lg_eg, rp_g2b, ei_g2b, obuf_b, 1, NEG, NBUS);
    // --- type 2: b2g (bus->gen) ---
    sgemm(cur_xb, Wl[l] + (size_t)2 * din * 256, xl_bus, NBUS, din);
    sgemm(cur_xg, Wr[l] + (size_t)2 * din * 256, xr_gen, NGEN, din);
    run_conv(2, xl_bus, xr_gen, We[l] + 3072, att[l] + 512, temp[l] + 2,
             lg_eg, rp_b2g, ei_b2g, obuf_g, 0, NEG, NGEN);
    // --- node update ---
    if (l < 2) {
      const float* rpw_b = (l == 0) ? rp0_w : nullptr;
      const float* rpb_b = (l == 0) ? rp0_b : nullptr;
      const float* rpw_g = (l == 0) ? rp0_w + 32 * 256 : nullptr;
      const float* rpb_g = (l == 0) ? rp0_b + 256 : nullptr;
      hipLaunchKernelGGL(ln_resid, dim3(NBUS), dim3(256), 0, stream,
                         obuf_b, bc[l], bc[l] + 256, lnw[l], lnb[l],
                         cur_xb, 32, rpw_b, rpb_b, 1, NBUS);
      hipLaunchKernelGGL(ln_resid, dim3(NGEN), dim3(256), 0, stream,
                         obuf_g, bc[l] + 512, nullptr, lnw[l] + 256, lnb[l] + 256,
                         cur_xg, 32, rpw_g, rpb_g, 1, NGEN);
      cur_xb = obuf_b;
      cur_xg = obuf_g;
    } else {
      float* out = (float*)d_out;
      hipLaunchKernelGGL(final_ln, dim3(NBUS), dim3(64), 0, stream,
                         obuf_b, bc[2], bc[2] + 64, lnw[2], lnb[2],
                         cur_xb, rp2_w, rp2_b, out, NBUS);
      hipLaunchKernelGGL(final_ln, dim3(NGEN), dim3(64), 0, stream,
                         obuf_g, bc[2] + 128, nullptr, lnw[2] + 64, lnb[2] + 64,
                         cur_xg, rp2_w + 256 * 64, rp2_b + 64,
                         out + (size_t)NBUS * 64, NGEN);
    }
  }
}

// Round 3
// 1234.254 us; speedup vs baseline: 3.4160x; 1.3850x over previous
//
#include <hip/hip_runtime.h>
#include <math.h>

#define NBUS 30000
#define NGEN 6000
#define NEL 250000
#define NEG 12000

typedef unsigned short u16;
typedef __attribute__((ext_vector_type(8))) short bf16x8;
typedef __attribute__((ext_vector_type(4))) float f32x4;

__device__ __forceinline__ u16 f2b(float x) {  // fp32 -> bf16 RNE
  unsigned u = __float_as_uint(x);
  unsigned r = (u + 0x7FFFu + ((u >> 16) & 1u)) >> 16;
  return (u16)r;
}

__global__ void zeroi(int* __restrict__ p, int n) {
  int i = blockIdx.x * blockDim.x + threadIdx.x;
  int st = gridDim.x * blockDim.x;
  for (; i < n; i += st) p[i] = 0;
}

__global__ void hist_k(const int* __restrict__ dst, int* __restrict__ cnt, int E) {
  int i = blockIdx.x * blockDim.x + threadIdx.x;
  if (i < E) atomicAdd(&cnt[dst[i]], 1);
}

__global__ __launch_bounds__(1024) void scan_k(
    const int* __restrict__ cnt, int* __restrict__ rowptr,
    int* __restrict__ cursor, int n) {
  __shared__ int wtot[16];
  __shared__ int s_carry;
  int tid = threadIdx.x, lane = tid & 63, wv = tid >> 6;
  if (tid == 0) { s_carry = 0; rowptr[0] = 0; }
  __syncthreads();
  for (int base = 0; base < n; base += 1024) {
    int i = base + tid;
    int v = (i < n) ? cnt[i] : 0;
    int x = v;
#pragma unroll
    for (int off = 1; off < 64; off <<= 1) {
      int y = __shfl_up(x, off, 64);
      if (lane >= off) x += y;
    }
    if (lane == 63) wtot[wv] = x;
    __syncthreads();
    if (tid < 16) {
      int t = wtot[tid];
#pragma unroll
      for (int off = 1; off < 16; off <<= 1) {
        int y = __shfl_up(t, off, 64);
        if (tid >= off) t += y;
      }
      wtot[tid] = t;
    }
    __syncthreads();
    int woff = (wv == 0) ? 0 : wtot[wv - 1];
    int incl = s_carry + woff + x;
    if (i < n) { rowptr[i + 1] = incl; cursor[i] = incl - v; }
    __syncthreads();
    if (tid == 0) s_carry += wtot[15];
    __syncthreads();
  }
}

__global__ void scatter_k(const int* __restrict__ dst, int* __restrict__ cursor,
                          int* __restrict__ eidx, int E) {
  int i = blockIdx.x * blockDim.x + threadIdx.x;
  if (i < E) {
    int p = atomicAdd(&cursor[dst[i]], 1);
    eidx[p] = i;
  }
}

__global__ void gen_proj(const float* __restrict__ x, const float* __restrict__ w,
                         const float* __restrict__ b, float* __restrict__ o) {
  int idx = blockIdx.x * blockDim.x + threadIdx.x;
  if (idx >= NGEN * 32) return;
  int i = idx >> 5, c = idx & 31;
  float acc = b[c];
#pragma unroll
  for (int k = 0; k < 16; ++k) acc += x[i * 16 + k] * w[k * 32 + c];
  o[idx] = acc;
}

// Pack + transpose + bf16-convert the 6 weight slices (each [K][256]) into
// Wt[1536][K]: g0=Wl s0, g1=Wr s0, g2=Wr s1, g3=Wl s2, g4=Wl s1, g5=Wr s2.
__global__ void pack_w(const float* __restrict__ Wl, const float* __restrict__ Wr,
                       u16* __restrict__ Wt, int K, int Kshift) {
  int tid = blockIdx.x * 256 + threadIdx.x;
  if (tid >= 6 * K * 256) return;
  int n = tid & 255;
  int k = (tid >> 8) & (K - 1);
  int g = tid >> (8 + Kshift);
  size_t sl = (size_t)K * 256;
  const float* src =
      (g == 0) ? Wl :
      (g == 1) ? Wr :
      (g == 2) ? Wr + sl :
      (g == 3) ? Wl + 2 * sl :
      (g == 4) ? Wl + sl : Wr + 2 * sl;
  Wt[((size_t)(g * 256 + n)) * K + k] = f2b(src[(size_t)k * 256 + n]);
}

// C[M][ldc] (fp32) = A[M][K] (fp32, bf16-converted in staging) @ Wt^T
// (Wt pre-transposed bf16 [N][K]). Tile 128x128, 4 waves 2x2 of 64x64,
// mfma_f32_16x16x32_bf16, BK=32. LDS rows padded to 40 shorts (bank-safe).
__global__ __launch_bounds__(256) void gemm_bf16(
    const float* __restrict__ A, const u16* __restrict__ Wt,
    float* __restrict__ C, int M, int K, int ldc)
{
  __shared__ u16 As[128][40];
  __shared__ u16 Bs[128][40];
  const int t = threadIdx.x;
  const int bm = blockIdx.x * 128;
  const int bn = blockIdx.y * 128;
  const int lane = t & 63, w = t >> 6;
  const int wm = (w & 1) * 64, wn = (w >> 1) * 64;
  const int lr = lane & 15, q = lane >> 4;
  f32x4 acc[4][4] = {};
  const int ar = t >> 2, akc = (t & 3) * 8;
  for (int k0 = 0; k0 < K; k0 += 32) {
    // stage A tile (fp32 -> bf16), rows bm..bm+127, k0..k0+31
#pragma unroll
    for (int rr = 0; rr < 128; rr += 64) {
      int gr = bm + ar + rr; if (gr > M - 1) gr = M - 1;
      const float* sp = A + (size_t)gr * K + k0 + akc;
      float4 f0 = *(const float4*)sp;
      float4 f1 = *(const float4*)(sp + 4);
      u16* dp = &As[ar + rr][akc];
      dp[0] = f2b(f0.x); dp[1] = f2b(f0.y); dp[2] = f2b(f0.z); dp[3] = f2b(f0.w);
      dp[4] = f2b(f1.x); dp[5] = f2b(f1.y); dp[6] = f2b(f1.z); dp[7] = f2b(f1.w);
    }
    // stage B tile (already bf16 [n][k]), n-rows bn..bn+127
#pragma unroll
    for (int c = t; c < 512; c += 256) {
      int nr = c >> 2, kc = (c & 3) * 8;
      *(bf16x8*)&Bs[nr][kc] =
          *(const bf16x8*)(Wt + (size_t)(bn + nr) * K + k0 + kc);
    }
    __syncthreads();
    bf16x8 af[4], bg[4];
#pragma unroll
    for (int i = 0; i < 4; ++i)
      af[i] = *(const bf16x8*)&As[wm + i * 16 + lr][q * 8];
#pragma unroll
    for (int j = 0; j < 4; ++j)
      bg[j] = *(const bf16x8*)&Bs[wn + j * 16 + lr][q * 8];
#pragma unroll
    for (int i = 0; i < 4; ++i)
#pragma unroll
      for (int j = 0; j < 4; ++j)
        acc[i][j] = __builtin_amdgcn_mfma_f32_16x16x32_bf16(
            af[i], bg[j], acc[i][j], 0, 0, 0);
    __syncthreads();
  }
#pragma unroll
  for (int i = 0; i < 4; ++i) {
    int row0 = bm + wm + i * 16 + q * 4;
#pragma unroll
    for (int j = 0; j < 4; ++j) {
      int col = bn + wn + j * 16 + lr;
#pragma unroll
      for (int r = 0; r < 4; ++r) {
        int row = row0 + r;
        if (row < M) C[(size_t)row * ldc + col] = acc[i][j][r];
      }
    }
  }
}

// One wave per edge: per-head attention logits -> lg[E][4].
__global__ __launch_bounds__(256) void edge_logits(
    const int* __restrict__ src, const int* __restrict__ dst,
    const float* __restrict__ ea,
    const float* __restrict__ xl, int ldl,
    const float* __restrict__ xr, int ldr,
    const float* __restrict__ We, const float* __restrict__ att,
    const float* __restrict__ tptr,
    float* __restrict__ logits, int E)
{
  int wid = (blockIdx.x * 256 + threadIdx.x) >> 6;
  int lane = threadIdx.x & 63;
  if (wid >= E) return;
  int s = src[wid], d = dst[wid];
  float temp = *tptr;
  const float* e = ea + (size_t)wid * 6;
  float e0 = e[0], e1 = e[1], e2 = e[2], e3 = e[3], e4 = e[4];
  float e5 = temp / fmaxf(e3, 1e-6f);  // physics prior overwrites col 5
  int c0 = lane << 2;
  float4 a = *(const float4*)(xl + (size_t)s * ldl + c0);
  float4 b = *(const float4*)(xr + (size_t)d * ldr + c0);
  float4 w0 = *(const float4*)(We + c0);
  float4 w1 = *(const float4*)(We + 256 + c0);
  float4 w2 = *(const float4*)(We + 512 + c0);
  float4 w3 = *(const float4*)(We + 768 + c0);
  float4 w4 = *(const float4*)(We + 1024 + c0);
  float4 w5 = *(const float4*)(We + 1280 + c0);
  float m0 = a.x + b.x + e0*w0.x + e1*w1.x + e2*w2.x + e3*w3.x + e4*w4.x + e5*w5.x;
  float m1 = a.y + b.y + e0*w0.y + e1*w1.y + e2*w2.y + e3*w3.y + e4*w4.y + e5*w5.y;
  float m2 = a.z + b.z + e0*w0.z + e1*w1.z + e2*w2.z + e3*w3.z + e4*w4.z + e5*w5.z;
  float m3 = a.w + b.w + e0*w0.w + e1*w1.w + e2*w2.w + e3*w3.w + e4*w4.w + e5*w5.w;
  m0 = m0 > 0.f ? m0 : 0.2f * m0;
  m1 = m1 > 0.f ? m1 : 0.2f * m1;
  m2 = m2 > 0.f ? m2 : 0.2f * m2;
  m3 = m3 > 0.f ? m3 : 0.2f * m3;
  float4 av = *(const float4*)(att + c0);
  float p = m0*av.x + m1*av.y + m2*av.z + m3*av.w;
  p += __shfl_xor(p, 1);
  p += __shfl_xor(p, 2);
  p += __shfl_xor(p, 4);
  p += __shfl_xor(p, 8);
  if ((lane & 15) == 0) logits[(size_t)wid * 4 + (lane >> 4)] = p;
}

// One wave per destination node: softmax + weighted gather. No atomics.
__global__ __launch_bounds__(256) void node_aggr(
    const int* __restrict__ rowptr, const int* __restrict__ eidx,
    const int* __restrict__ src, const float* __restrict__ lg,
    const float* __restrict__ xl, int ldl, float* __restrict__ obuf,
    int accumulate, int N)
{
  int node = (blockIdx.x * 256 + threadIdx.x) >> 6;
  int lane = threadIdx.x & 63;
  if (node >= N) return;
  int beg = rowptr[node], end = rowptr[node + 1];
  int h = lane >> 4;
  int c0 = lane << 2;
  float mx = -INFINITY;
  for (int i = beg; i < end; ++i) {
    int e = eidx[i];
    mx = fmaxf(mx, lg[(size_t)e * 4 + h]);
  }
  if (!isfinite(mx)) mx = 0.f;
  float den = 0.f;
  float4 acc = make_float4(0.f, 0.f, 0.f, 0.f);
  for (int i = beg; i < end; ++i) {
    int e = eidx[i];
    float wq = expf(lg[(size_t)e * 4 + h] - mx);
    den += wq;
    int s = src[e];
    float4 x = *(const float4*)(xl + (size_t)s * ldl + c0);
    acc.x += wq * x.x; acc.y += wq * x.y; acc.z += wq * x.z; acc.w += wq * x.w;
  }
  float inv = 1.f / (den + 1e-16f);
  acc.x *= inv; acc.y *= inv; acc.z *= inv; acc.w *= inv;
  float* o = obuf + (size_t)node * 256 + c0;
  if (accumulate) {
    float4 p = *(const float4*)o;
    acc.x += p.x; acc.y += p.y; acc.z += p.z; acc.w += p.w;
  }
  *(float4*)o = acc;
}

// LN(256) + residual (direct or 32->256 proj) + optional ELU, in place.
__global__ __launch_bounds__(256) void ln_resid(
    float* __restrict__ io,
    const float* __restrict__ b1, const float* __restrict__ b2,
    const float* __restrict__ lnw, const float* __restrict__ lnb,
    const float* __restrict__ resx, int dres,
    const float* __restrict__ rp_w, const float* __restrict__ rp_b,
    int do_elu, int N)
{
  int i = blockIdx.x;
  if (i >= N) return;
  int c = threadIdx.x;
  __shared__ float red[4];
  __shared__ float rrow[32];
  float v = io[(size_t)i * 256 + c] + b1[c];
  if (b2) v += b2[c];
  float s = v;
#pragma unroll
  for (int m = 32; m >= 1; m >>= 1) s += __shfl_xor(s, m);
  if ((c & 63) == 0) red[c >> 6] = s;
  __syncthreads();
  float mu = (red[0] + red[1] + red[2] + red[3]) * (1.f / 256.f);
  __syncthreads();
  float dv = v - mu;
  float q = dv * dv;
#pragma unroll
  for (int m = 32; m >= 1; m >>= 1) q += __shfl_xor(q, m);
  if ((c & 63) == 0) red[c >> 6] = q;
  if (rp_w && c < dres) rrow[c] = resx[(size_t)i * dres + c];
  __syncthreads();
  float var = (red[0] + red[1] + red[2] + red[3]) * (1.f / 256.f);
  float y = dv * rsqrtf(var + 1e-5f) * lnw[c] + lnb[c];
  if (rp_w) {
    float r = rp_b[c];
    for (int k = 0; k < dres; ++k) r += rrow[k] * rp_w[k * 256 + c];
    y += r;
  } else {
    y += resx[(size_t)i * 256 + c];
  }
  if (do_elu) y = (y > 0.f) ? y : expm1f(y);
  io[(size_t)i * 256 + c] = y;
}

// Layer 2: head-mean + bias + LN(64) + rp2 residual (256->64), write d_out.
__global__ __launch_bounds__(64) void final_ln(
    const float* __restrict__ obuf,
    const float* __restrict__ b1, const float* __restrict__ b2,
    const float* __restrict__ lnw, const float* __restrict__ lnb,
    const float* __restrict__ resx,
    const float* __restrict__ rp_w, const float* __restrict__ rp_b,
    float* __restrict__ out, int N)
{
  int i = blockIdx.x;
  if (i >= N) return;
  int c = threadIdx.x;
  __shared__ float rrow[256];
  const float* orow = obuf + (size_t)i * 256;
  float v = 0.25f * (orow[c] + orow[64 + c] + orow[128 + c] + orow[192 + c]);
  v += b1[c];
  if (b2) v += b2[c];
  float s = v;
#pragma unroll
  for (int m = 32; m >= 1; m >>= 1) s += __shfl_xor(s, m);
  float mu = s * (1.f / 64.f);
  float dv = v - mu;
  float q = dv * dv;
#pragma unroll
  for (int m = 32; m >= 1; m >>= 1) q += __shfl_xor(q, m);
  float var = q * (1.f / 64.f);
  float y = dv * rsqrtf(var + 1e-5f) * lnw[c] + lnb[c];
  *(float4*)&rrow[c << 2] = *(const float4*)(resx + (size_t)i * 256 + (c << 2));
  __syncthreads();
  float r = rp_b[c];
#pragma unroll 8
  for (int k = 0; k < 256; ++k) r += rrow[k] * rp_w[k * 64 + c];
  out[(size_t)i * 64 + c] = y + r;
}

extern "C" void kernel_launch(void* const* d_in, const int* in_sizes, int n_in,
                              void* d_out, int out_size, void* d_ws, size_t ws_size,
                              hipStream_t stream) {
  const float* x_bus = (const float*)d_in[0];
  const float* x_gen = (const float*)d_in[1];
  const float* ea[3] = {(const float*)d_in[2], (const float*)d_in[3], (const float*)d_in[4]};
  const float* pw = (const float*)d_in[5];
  const float* pb = (const float*)d_in[6];
  const float* Wl[3] = {(const float*)d_in[7], (const float*)d_in[15], (const float*)d_in[23]};
  const float* Wr[3] = {(const float*)d_in[8], (const float*)d_in[16], (const float*)d_in[24]};
  const float* We[3] = {(const float*)d_in[9], (const float*)d_in[17], (const float*)d_in[25]};
  const float* att[3] = {(const float*)d_in[10], (const float*)d_in[18], (const float*)d_in[26]};
  const float* bc[3] = {(const float*)d_in[11], (const float*)d_in[19], (const float*)d_in[27]};
  const float* temp[3] = {(const float*)d_in[12], (const float*)d_in[20], (const float*)d_in[28]};
  const float* lnw[3] = {(const float*)d_in[13], (const float*)d_in[21], (const float*)d_in[29]};
  const float* lnb[3] = {(const float*)d_in[14], (const float*)d_in[22], (const float*)d_in[30]};
  const float* rp0_w = (const float*)d_in[31];
  const float* rp0_b = (const float*)d_in[32];
  const float* rp2_w = (const float*)d_in[33];
  const float* rp2_b = (const float*)d_in[34];
  const int* srcs[3] = {(const int*)d_in[35], (const int*)d_in[37], (const int*)d_in[39]};
  const int* dsts[3] = {(const int*)d_in[36], (const int*)d_in[38], (const int*)d_in[40]};

  float* ws = (float*)d_ws;
  size_t off = 0;
  auto alloc = [&](size_t n) { float* p = ws + off; off += n; return p; };
  float* xbA = alloc((size_t)NBUS * 256);
  float* xbB = alloc((size_t)NBUS * 256);
  float* Pbig = alloc((size_t)NBUS * 512);   // packed xl|xr for conv0; halves reused later
  float* xgA = alloc((size_t)NGEN * 256);
  float* xgB = alloc((size_t)NGEN * 256);
  float* xl_gen = alloc((size_t)NGEN * 256);
  float* xr_gen = alloc((size_t)NGEN * 256);
  float* xg0 = alloc((size_t)NGEN * 32);
  float* lg_line = alloc((size_t)NEL * 4);
  float* lg_eg = alloc((size_t)NEG * 4);
  u16* Wt = (u16*)alloc((size_t)1536 * 256 / 2);
  int* cw_line = (int*)alloc(NBUS);
  int* rp_line = (int*)alloc(NBUS + 1);
  int* ei_line = (int*)alloc(NEL);
  int* cw_g2b = (int*)alloc(NBUS);
  int* rp_g2b = (int*)alloc(NBUS + 1);
  int* ei_g2b = (int*)alloc(NEG);
  int* cw_b2g = (int*)alloc(NGEN);
  int* rp_b2g = (int*)alloc(NGEN + 1);
  int* ei_b2g = (int*)alloc(NEG);
  float* xr1buf = Pbig + (size_t)NBUS * 256;  // raw region reuse after conv0
  float* xl2buf = Pbig;                        // raw region reuse after conv1
  (void)ws_size; (void)in_sizes; (void)n_in; (void)out_size;

  auto build_csr = [&](const int* dst, int* cw, int* rp, int* ei, int E, int N) {
    hipLaunchKernelGGL(zeroi, dim3(64), dim3(1024), 0, stream, cw, N);
    hipLaunchKernelGGL(hist_k, dim3((E + 255) / 256), dim3(256), 0, stream, dst, cw, E);
    hipLaunchKernelGGL(scan_k, dim3(1), dim3(1024), 0, stream, cw, rp, cw, N);
    hipLaunchKernelGGL(scatter_k, dim3((E + 255) / 256), dim3(256), 0, stream, dst, cw, ei, E);
  };
  build_csr(dsts[0], cw_line, rp_line, ei_line, NEL, NBUS);
  build_csr(dsts[1], cw_g2b, rp_g2b, ei_g2b, NEG, NBUS);
  build_csr(dsts[2], cw_b2g, rp_b2g, ei_b2g, NEG, NGEN);

  auto gemm = [&](const float* A, const u16* Wslice, float* Cm, int M, int K, int N) {
    dim3 g((M + 127) / 128, N / 128);
    hipLaunchKernelGGL(gemm_bf16, g, dim3(256), 0, stream, A, Wslice, Cm, M, K, N);
  };
  auto conv = [&](int type, const float* xlb, int ldl, const float* xrb, int ldr,
                  const float* Wel, const float* attl, const float* templ,
                  float* lg, const int* rp, const int* ei,
                  float* obuf, int accumulate, int E, int N) {
    hipLaunchKernelGGL(edge_logits, dim3((E + 3) / 4), dim3(256), 0, stream,
                       srcs[type], dsts[type], ea[type], xlb, ldl, xrb, ldr,
                       Wel, attl, templ, lg, E);
    hipLaunchKernelGGL(node_aggr, dim3((N + 3) / 4), dim3(256), 0, stream,
                       rp, ei, srcs[type], lg, xlb, ldl, obuf, accumulate, N);
  };

  hipLaunchKernelGGL(gen_proj, dim3((NGEN * 32 + 255) / 256), dim3(256), 0, stream,
                     x_gen, pw, pb, xg0);

  const int din_l[3] = {32, 256, 256};
  const int ksh_l[3] = {5, 8, 8};
  const float* cur_xb = x_bus;
  const float* cur_xg = xg0;
  for (int l = 0; l < 3; ++l) {
    const int K = din_l[l];
    float* obuf_b = (l == 1) ? xbB : xbA;
    float* obuf_g = (l == 1) ? xgB : xgA;
    hipLaunchKernelGGL(pack_w, dim3(6 * K), dim3(256), 0, stream,
                       Wl[l], Wr[l], Wt, K, ksh_l[l]);
    // --- type 0: line (bus->bus), packed N=512 (xl cols 0-255, xr 256-511) ---
    gemm(cur_xb, Wt, Pbig, NBUS, K, 512);
    conv(0, Pbig, 512, Pbig + 256, 512, We[l], att[l], temp[l],
         lg_line, rp_line, ei_line, obuf_b, 0, NEL, NBUS);
    // --- type 1: g2b (gen->bus), accumulate into obuf_b ---
    gemm(cur_xb, Wt + (size_t)512 * K, xr1buf, NBUS, K, 256);
    gemm(cur_xg, Wt + (size_t)1024 * K, xl_gen, NGEN, K, 256);
    conv(1, xl_gen, 256, xr1buf, 256, We[l] + 1536, att[l] + 256, temp[l] + 1,
         lg_eg, rp_g2b, ei_g2b, obuf_b, 1, NEG, NBUS);
    // --- type 2: b2g (bus->gen) ---
    gemm(cur_xb, Wt + (size_t)768 * K, xl2buf, NBUS, K, 256);
    gemm(cur_xg, Wt + (size_t)1280 * K, xr_gen, NGEN, K, 256);
    conv(2, xl2buf, 256, xr_gen, 256, We[l] + 3072, att[l] + 512, temp[l] + 2,
         lg_eg, rp_b2g, ei_b2g, obuf_g, 0, NEG, NGEN);
    // --- node update ---
    if (l < 2) {
      const float* rpw_b = (l == 0) ? rp0_w : nullptr;
      const float* rpb_b = (l == 0) ? rp0_b : nullptr;
      const float* rpw_g = (l == 0) ? rp0_w + 32 * 256 : nullptr;
      const float* rpb_g = (l == 0) ? rp0_b + 256 : nullptr;
      hipLaunchKernelGGL(ln_resid, dim3(NBUS), dim3(256), 0, stream,
                         obuf_b, bc[l], bc[l] + 256, lnw[l], lnb[l],
                         cur_xb, 32, rpw_b, rpb_b, 1, NBUS);
      hipLaunchKernelGGL(ln_resid, dim3(NGEN), dim3(256), 0, stream,
                         obuf_g, bc[l] + 512, nullptr, lnw[l] + 256, lnb[l] + 256,
                         cur_xg, 32, rpw_g, rpb_g, 1, NGEN);
      cur_xb = obuf_b;
      cur_xg = obuf_g;
    } else {
      float* out = (float*)d_out;
      hipLaunchKernelGGL(final_ln, dim3(NBUS), dim3(64), 0, stream,
                         obuf_b, bc[2], bc[2] + 64, lnw[2], lnb[2],
                         cur_xb, rp2_w, rp2_b, out, NBUS);
      hipLaunchKernelGGL(final_ln, dim3(NGEN), dim3(64), 0, stream,
                         obuf_g, bc[2] + 128, nullptr, lnw[2] + 64, lnb[2] + 64,
                         cur_xg, rp2_w + 256 * 64, rp2_b + 64,
                         out + (size_t)NBUS * 64, NGEN);
    }
  }
}